// Round 3
// baseline (731.238 us; speedup 1.0000x reference)
//
#include <hip/hip_runtime.h>
#include <hip/hip_bf16.h>

// Swin shifted-window attention, fully fused per-window. FP32 global IO,
// bf16 MFMA internals. B=4, H=W=256, C=192, NH=6, HD=32, WS=8, SHIFT=4, "SW".
// One block = one window (64 tokens), 384 threads = 6 waves, wave w = head w.

typedef __bf16 bf16x8 __attribute__((ext_vector_type(8)));
typedef float  f32x4  __attribute__((ext_vector_type(4)));

static __device__ __forceinline__ unsigned short f2bf(float f) {
    __bf16 h = (__bf16)f;                       // RNE f32->bf16
    return __builtin_bit_cast(unsigned short, h);
}

// ---------------------------------------------------------------------------
// LDS layout (ushort units):
//   QS  [64][200]  @ 0      (q, row=token, col=feat, pad 200)  -- reused as OS
//   KS  [64][200]  @ 12800
//   VT  [192][72]  @ 25600  (v transposed: row=feat, col=token, pad 72)
//   PS  [6][64][72]@ 39424  (per-head P)  -- first 12800 aliased as XS (x tile)
//   RELF[1350] f32 @ 67072  (rel_pos table, 225*6, kept fp32)
// total 69772 ushort = 139544 B  (< 160 KiB gfx950 LDS)

__global__ __launch_bounds__(384)
void wmsa_fused(const float* __restrict__ x,        // [4,256,256,192]
                const float* __restrict__ wq,       // [192][576]
                const float* __restrict__ b_qkv,    // [576]
                const float* __restrict__ wl,       // [192][192]
                const float* __restrict__ b_lin,    // [192]
                const float* __restrict__ rel_pos,  // [225*6]
                float* __restrict__ out)            // [4,256,256,192]
{
    __shared__ __align__(16) unsigned short smem[69772];
    unsigned short* QS  = smem;            // also OS
    unsigned short* KS  = smem + 12800;
    unsigned short* VT  = smem + 25600;
    unsigned short* PS  = smem + 39424;
    unsigned short* XS  = smem + 39424;    // alias over PS (phase 1-2 only)
    float*          RELF = (float*)(smem + 67072);

    const int tid  = threadIdx.x;
    const int lane = tid & 63;
    const int w    = tid >> 6;     // wave id == head id, 0..5
    const int l15  = lane & 15;
    const int quad = lane >> 4;

    const int bx = blockIdx.x;     // 4096 = 4 * 32 * 32
    const int b  = bx >> 10;
    const int wh = (bx >> 5) & 31;
    const int ww = bx & 31;

    // ---- Phase 1: stage rolled x rows (64 tokens x 192, fp32 -> bf16) + rel_pos
    // shifted image: xs[h][w] = x[(h+4)%256][(w+4)%256]
    for (int i = tid; i < 3072; i += 384) {           // 64 rows * 48 float4 chunks
        int row = i / 48, cc = i % 48;
        int hs = wh * 8 + (row >> 3), wsx = ww * 8 + (row & 7);
        int ho = (hs + 4) & 255,      wo  = (wsx + 4) & 255;
        float4 v = *(const float4*)(x + ((((b << 8) + ho) << 8) + wo) * 192 + cc * 4);
        ushort4 p;
        p.x = f2bf(v.x); p.y = f2bf(v.y); p.z = f2bf(v.z); p.w = f2bf(v.w);
        *(ushort4*)(XS + row * 200 + cc * 4) = p;
    }
    for (int i = tid; i < 1350; i += 384) RELF[i] = rel_pos[i];
    __syncthreads();

    // ---- Phase 2: qkv = xs @ Wqkv + b_qkv  -> QS / KS / VT
    // wave w handles ntiles [6w, 6w+6).  B-frag gathered from global fp32 wq:
    // bfr[j] = (bf16)Wqkv[ks*32 + quad*8 + j][nt*16 + l15]
    #pragma unroll 1
    for (int ntl = 0; ntl < 6; ++ntl) {
        int nt = w * 6 + ntl;                          // 0..35
        f32x4 acc[4];
        #pragma unroll
        for (int mt = 0; mt < 4; ++mt) acc[mt] = (f32x4){0.f, 0.f, 0.f, 0.f};
        #pragma unroll
        for (int ks = 0; ks < 6; ++ks) {
            const float* wp = wq + (ks * 32 + quad * 8) * 576 + nt * 16 + l15;
            bf16x8 bfr;
            #pragma unroll
            for (int j = 0; j < 8; ++j) bfr[j] = (__bf16)wp[j * 576];
            #pragma unroll
            for (int mt = 0; mt < 4; ++mt) {
                bf16x8 afr = *(const bf16x8*)(XS + (mt * 16 + l15) * 200 + ks * 32 + quad * 8);
                acc[mt] = __builtin_amdgcn_mfma_f32_16x16x32_bf16(afr, bfr, acc[mt], 0, 0, 0);
            }
        }
        int col  = nt * 16 + l15;                      // global qkv col 0..575
        float bv = b_qkv[col];
        int sidx = col / 192;                          // 0=q 1=k 2=v (uniform per nt)
        int cin  = col % 192;
        #pragma unroll
        for (int mt = 0; mt < 4; ++mt) {
            if (sidx == 2) {                           // V: store transposed, 4 tokens packed
                ushort4 pk;
                pk.x = f2bf(acc[mt][0] + bv);
                pk.y = f2bf(acc[mt][1] + bv);
                pk.z = f2bf(acc[mt][2] + bv);
                pk.w = f2bf(acc[mt][3] + bv);
                *(ushort4*)(VT + cin * 72 + mt * 16 + quad * 4) = pk;
            } else {
                unsigned short* dst = (sidx == 0) ? QS : KS;
                #pragma unroll
                for (int r = 0; r < 4; ++r)
                    dst[(mt * 16 + quad * 4 + r) * 200 + cin] = f2bf(acc[mt][r] + bv);
            }
        }
    }
    __syncthreads();

    // ---- Phase 3a: S = Q Kt * scale + bias, mask, softmax -> PS[w] (wave = head)
    {
        const float SCALE = 0.17677669529663687f;      // 32^-0.5
        f32x4 sa[4][4];
        #pragma unroll
        for (int mt = 0; mt < 4; ++mt)
            #pragma unroll
            for (int nt = 0; nt < 4; ++nt) sa[mt][nt] = (f32x4){0.f, 0.f, 0.f, 0.f};
        bf16x8 kf[4];
        #pragma unroll
        for (int nt = 0; nt < 4; ++nt)
            kf[nt] = *(const bf16x8*)(KS + (nt * 16 + l15) * 200 + w * 32 + quad * 8);
        #pragma unroll
        for (int mt = 0; mt < 4; ++mt) {
            bf16x8 afr = *(const bf16x8*)(QS + (mt * 16 + l15) * 200 + w * 32 + quad * 8);
            #pragma unroll
            for (int nt = 0; nt < 4; ++nt)
                sa[mt][nt] = __builtin_amdgcn_mfma_f32_16x16x32_bf16(afr, kf[nt], sa[mt][nt], 0, 0, 0);
        }
        // bias + mask  (C-layout: row = mt*16+quad*4+r, col = nt*16+l15)
        float sv[4][4][4];
        const bool mH = (wh == 31), mW = (ww == 31);
        #pragma unroll
        for (int mt = 0; mt < 4; ++mt)
            #pragma unroll
            for (int nt = 0; nt < 4; ++nt)
                #pragma unroll
                for (int r = 0; r < 4; ++r) {
                    int row = mt * 16 + quad * 4 + r;
                    int col = nt * 16 + l15;
                    int r1 = row >> 3, c1 = row & 7, r2 = col >> 3, c2 = col & 7;
                    float v = sa[mt][nt][r] * SCALE
                            + RELF[((r1 - r2 + 7) * 15 + (c1 - c2 + 7)) * 6 + w];
                    if ((mH && ((r1 < 4) != (r2 < 4))) || (mW && ((c1 < 4) != (c2 < 4))))
                        v = -1e30f;
                    sv[mt][nt][r] = v;
                }
        // row softmax: each row lives in 4 regs x 16 lanes of one quad-group
        #pragma unroll
        for (int mt = 0; mt < 4; ++mt)
            #pragma unroll
            for (int r = 0; r < 4; ++r) {
                float m = fmaxf(fmaxf(sv[mt][0][r], sv[mt][1][r]),
                                fmaxf(sv[mt][2][r], sv[mt][3][r]));
                m = fmaxf(m, __shfl_xor(m, 1));
                m = fmaxf(m, __shfl_xor(m, 2));
                m = fmaxf(m, __shfl_xor(m, 4));
                m = fmaxf(m, __shfl_xor(m, 8));
                float s = 0.f;
                #pragma unroll
                for (int nt = 0; nt < 4; ++nt) {
                    float p = __expf(sv[mt][nt][r] - m);
                    sv[mt][nt][r] = p;
                    s += p;
                }
                s += __shfl_xor(s, 1);
                s += __shfl_xor(s, 2);
                s += __shfl_xor(s, 4);
                s += __shfl_xor(s, 8);
                float inv = 1.f / s;
                #pragma unroll
                for (int nt = 0; nt < 4; ++nt) sv[mt][nt][r] *= inv;
            }
        unsigned short* myP = PS + w * 4608;           // 64*72
        #pragma unroll
        for (int mt = 0; mt < 4; ++mt)
            #pragma unroll
            for (int nt = 0; nt < 4; ++nt)
                #pragma unroll
                for (int r = 0; r < 4; ++r)
                    myP[(mt * 16 + quad * 4 + r) * 72 + nt * 16 + l15] = f2bf(sv[mt][nt][r]);
    }
    __syncthreads();   // all QS/KS reads done before OS (=QS) is overwritten

    // ---- Phase 3b: O = P @ V  -> OS (over QS region)
    {
        f32x4 oa[4][2];
        #pragma unroll
        for (int mt = 0; mt < 4; ++mt) { oa[mt][0] = (f32x4){0.f,0.f,0.f,0.f}; oa[mt][1] = (f32x4){0.f,0.f,0.f,0.f}; }
        unsigned short* myP = PS + w * 4608;
        #pragma unroll
        for (int ks2 = 0; ks2 < 2; ++ks2) {
            bf16x8 vf[2];
            #pragma unroll
            for (int nt2 = 0; nt2 < 2; ++nt2)
                vf[nt2] = *(const bf16x8*)(VT + (w * 32 + nt2 * 16 + l15) * 72 + ks2 * 32 + quad * 8);
            #pragma unroll
            for (int mt = 0; mt < 4; ++mt) {
                bf16x8 pf = *(const bf16x8*)(myP + (mt * 16 + l15) * 72 + ks2 * 32 + quad * 8);
                #pragma unroll
                for (int nt2 = 0; nt2 < 2; ++nt2)
                    oa[mt][nt2] = __builtin_amdgcn_mfma_f32_16x16x32_bf16(pf, vf[nt2], oa[mt][nt2], 0, 0, 0);
            }
        }
        unsigned short* OS = QS;
        #pragma unroll
        for (int mt = 0; mt < 4; ++mt)
            #pragma unroll
            for (int nt2 = 0; nt2 < 2; ++nt2)
                #pragma unroll
                for (int r = 0; r < 4; ++r)
                    OS[(mt * 16 + quad * 4 + r) * 200 + w * 32 + nt2 * 16 + l15] = f2bf(oa[mt][nt2][r]);
    }
    __syncthreads();

    // ---- Phase 4: out = OS @ w_lin + b_lin, inverse roll, fp32 store
    // B-frag gathered from global fp32 wl: bfr[j] = (bf16)Wlin[ks*32+quad*8+j][ntg*16+l15]
    {
        const unsigned short* OS = QS;
        #pragma unroll 1
        for (int nt2 = 0; nt2 < 2; ++nt2) {
            int ntg = w * 2 + nt2;                     // 0..11
            f32x4 acc[4];
            #pragma unroll
            for (int mt = 0; mt < 4; ++mt) acc[mt] = (f32x4){0.f, 0.f, 0.f, 0.f};
            #pragma unroll
            for (int ks = 0; ks < 6; ++ks) {
                const float* wp = wl + (ks * 32 + quad * 8) * 192 + ntg * 16 + l15;
                bf16x8 bfr;
                #pragma unroll
                for (int j = 0; j < 8; ++j) bfr[j] = (__bf16)wp[j * 192];
                #pragma unroll
                for (int mt = 0; mt < 4; ++mt) {
                    bf16x8 afr = *(const bf16x8*)(OS + (mt * 16 + l15) * 200 + ks * 32 + quad * 8);
                    acc[mt] = __builtin_amdgcn_mfma_f32_16x16x32_bf16(afr, bfr, acc[mt], 0, 0, 0);
                }
            }
            int col  = ntg * 16 + l15;                 // 0..191
            float bv = b_lin[col];
            #pragma unroll
            for (int mt = 0; mt < 4; ++mt)
                #pragma unroll
                for (int r = 0; r < 4; ++r) {
                    int row = mt * 16 + quad * 4 + r;
                    int hs = wh * 8 + (row >> 3), wsx = ww * 8 + (row & 7);
                    int ho = (hs + 4) & 255,      wo  = (wsx + 4) & 255;
                    out[((((b << 8) + ho) << 8) + wo) * 192 + col] = acc[mt][r] + bv;
                }
        }
    }
}

// ---------------------------------------------------------------------------
extern "C" void kernel_launch(void* const* d_in, const int* in_sizes, int n_in,
                              void* d_out, int out_size, void* d_ws, size_t ws_size,
                              hipStream_t stream) {
    const float* x  = (const float*)d_in[0];   // [4,256,256,192] fp32
    const float* wq = (const float*)d_in[1];   // [192,576]
    const float* bq = (const float*)d_in[2];   // [576]
    const float* wl = (const float*)d_in[3];   // [192,192]
    const float* bl = (const float*)d_in[4];   // [192]
    const float* rp = (const float*)d_in[5];   // [225,6]
    (void)d_ws; (void)ws_size; (void)in_sizes; (void)n_in;

    wmsa_fused<<<4096, 384, 0, stream>>>(x, wq, bq, wl, bl, rp, (float*)d_out);
}